// Round 7
// baseline (125.174 us; speedup 1.0000x reference)
//
#include <hip/hip_runtime.h>
#include <hip/hip_bf16.h>
#include <cmath>

typedef unsigned short u16;
typedef __attribute__((ext_vector_type(8))) short short8v;
typedef __attribute__((ext_vector_type(4))) unsigned short ushort4v;
typedef __attribute__((ext_vector_type(8))) unsigned short ushort8v;
typedef __attribute__((ext_vector_type(4))) float f32x4;

#define NPIX 784      // 28*28
#define KP   800      // padded K (25 k-frags of 32)
#define NH   800      // HID
#define STRIDE 808    // LDS row stride for h, bf16 elems (1616 B rows, 16B-aligned)

__device__ __forceinline__ u16 f2bf(float f) {
    union { float f; unsigned int u; } v; v.f = f;
    unsigned int u = v.u;
    unsigned int r = (u + 0x7FFFu + ((u >> 16) & 1u)) >> 16;   // RNE
    return (u16)r;
}

// two float4 -> 8 bf16 via v_cvt_pk_bf16_f32
__device__ __forceinline__ short8v cvt8(float4 v0, float4 v1) {
    union { __hip_bfloat162 h; ushort2 u; } a, b, c, d;
    a.h = __float22bfloat162_rn(make_float2(v0.x, v0.y));
    b.h = __float22bfloat162_rn(make_float2(v0.z, v0.w));
    c.h = __float22bfloat162_rn(make_float2(v1.x, v1.y));
    d.h = __float22bfloat162_rn(make_float2(v1.z, v1.w));
    short8v r;
    r[0] = (short)a.u.x; r[1] = (short)a.u.y; r[2] = (short)b.u.x; r[3] = (short)b.u.y;
    r[4] = (short)c.u.x; r[5] = (short)c.u.y; r[6] = (short)d.u.x; r[7] = (short)d.u.y;
    return r;
}

// ---------------------------------------------------------------------------
// Kernel 1: kre = Re(ifft2(ifftshift(tmask))), separable 28-pt DFT, 1 block.
// Sets flag = 1.0 if kre is (numerically) a delta -> conv is identity.
// ---------------------------------------------------------------------------
__global__ void k_kre(const float* __restrict__ MRE, const float* __restrict__ MIM,
                      float* __restrict__ KRE, float* __restrict__ FLAG)
{
    __shared__ float msre[784], msim[784], tre[784], tim[784];
    __shared__ float c28[28], s28[28];
    __shared__ int smax;

    const int t = threadIdx.x;   // blockDim = 832
    if (t < 28) {
        float th = (float)t * (6.283185307179586f / 28.0f);
        s28[t] = sinf(th);
        c28[t] = cosf(th);
    }
    if (t == 0) smax = 0;
    if (t < 784) {
        int r = t / 28, c = t - r * 28;
        int idx = ((r + 14) % 28) * 28 + ((c + 14) % 28);   // ifftshift
        msre[t] = MRE[idx];
        msim[t] = MIM[idx];
    }
    __syncthreads();
    if (t < 784) {
        int u = t / 28, cc = t - u * 28;
        float re = 0.f, im = 0.f;
        int ph = 0;
        for (int v = 0; v < 28; ++v) {
            float cr = c28[ph], ci = s28[ph];
            float ar = msre[u * 28 + v], ai = msim[u * 28 + v];
            re += ar * cr - ai * ci;
            im += ar * ci + ai * cr;
            ph += cc; if (ph >= 28) ph -= 28;
        }
        tre[t] = re; tim[t] = im;
    }
    __syncthreads();
    float dev = 0.f;
    if (t < 784) {
        int pr = t / 28, pc = t - pr * 28;
        float s = 0.f;
        int ph = 0;
        for (int u = 0; u < 28; ++u) {
            s += tre[u * 28 + pc] * c28[ph] - tim[u * 28 + pc] * s28[ph];
            ph += pr; if (ph >= 28) ph -= 28;
        }
        s *= (1.0f / 784.0f);
        KRE[t] = s;
        dev = fabsf(s - (t == 0 ? 1.0f : 0.0f));
    }
    #pragma unroll
    for (int m = 32; m >= 1; m >>= 1) dev = fmaxf(dev, __shfl_xor(dev, m, 64));
    if ((t & 63) == 0) atomicMax(&smax, __float_as_int(dev));
    __syncthreads();
    if (t == 0) FLAG[0] = (__int_as_float(smax) < 1e-4f) ? 1.0f : 0.0f;
}

// ---------------------------------------------------------------------------
// Kernel 2: w1_eff[c][k] packed into MFMA B-fragment order, bf16.
// ---------------------------------------------------------------------------
__global__ void k_w1pack(const float* __restrict__ W1, const float* __restrict__ KRE,
                         const float* __restrict__ FLAG, u16* __restrict__ W1P)
{
    const int c = blockIdx.x;    // 0..799
    const int t = threadIdx.x;   // 128
    const bool delta = (FLAG[0] > 0.5f);
    __shared__ float w1d[56 * 56];
    __shared__ float kr[784];

    if (delta) {
        if (t < 100) {
            int k0 = t * 8;
            ushort8v h;
            if (k0 + 7 < NPIX) {
                const float4* wp = (const float4*)(W1 + (size_t)c * NPIX + k0);
                float4 a = wp[0], b = wp[1];
                h[0] = f2bf(a.x); h[1] = f2bf(a.y); h[2] = f2bf(a.z); h[3] = f2bf(a.w);
                h[4] = f2bf(b.x); h[5] = f2bf(b.y); h[6] = f2bf(b.z); h[7] = f2bf(b.w);
            } else {
                #pragma unroll
                for (int e = 0; e < 8; ++e) {
                    int k = k0 + e;
                    h[e] = (k < NPIX) ? f2bf(W1[(size_t)c * NPIX + k]) : (u16)0;
                }
            }
            int kf = k0 >> 5, r = k0 & 31;
            int l  = ((r >> 3) << 4) | (c & 15);
            int nf = c >> 4;
            ((ushort8v*)W1P)[(nf * 25 + kf) * 64 + l] = h;
        }
        return;
    }
    for (int i = t; i < 784; i += 128) kr[i] = KRE[i];
    for (int i = t; i < 3136; i += 128) {
        int r = i / 56, cc = i - r * 56;
        w1d[i] = W1[(size_t)c * NPIX + (r % 28) * 28 + (cc % 28)];
    }
    __syncthreads();
    for (int k = t; k < KP; k += 128) {
        float v = 0.f;
        if (k < NPIX) {
            int krr = k / 28, kcc = k - krr * 28;
            for (int dr = 0; dr < 28; ++dr) {
                const float* wrow = &w1d[(krr + dr) * 56 + kcc];
                const float* krow = &kr[dr * 28];
                #pragma unroll 4
                for (int dc = 0; dc < 28; ++dc) v += wrow[dc] * krow[dc];
            }
        }
        int kf = k >> 5, r = k & 31;
        int l  = ((r >> 3) << 4) | (c & 15);
        int nf = c >> 4;
        W1P[(size_t)(((nf * 25 + kf) * 64 + l) << 3) | (r & 7)] = f2bf(v);
    }
}

// ---------------------------------------------------------------------------
// Kernel 2b: pack W4 (10 x 800 f32) into B-fragment order, 16-col tile,
// cols 10..15 zero. W4P[(kt*64 + l)*8 + e] = W4[lc][kt*32 + lk*8 + e].
// ---------------------------------------------------------------------------
__global__ void k_w4pack(const float* __restrict__ W4, u16* __restrict__ W4P)
{
    int i = blockIdx.x * 256 + threadIdx.x;   // (kt*64 + l), 1600 total
    if (i >= 1600) return;
    int l = i & 63, kt = i >> 6;
    int lc = l & 15, lk = l >> 4;
    ushort8v h;
    #pragma unroll
    for (int e = 0; e < 8; ++e) {
        int k = kt * 32 + lk * 8 + e;
        h[e] = (lc < 10) ? f2bf(W4[lc * NH + k]) : (u16)0;
    }
    ((ushort8v*)W4P)[i] = h;
}

// ---------------------------------------------------------------------------
// Kernel 3: fused GEMM1 + relu + (MFMA) GEMM2 + log_softmax.
// v7: NO X staging. A-fragments load directly from global X (two float4 per
//     m-frag = exactly the lane's 8 k-elements), cvt_pk f32->bf16 in-register.
//     Per kt the block touches 8 KB of X shared by all 10 waves in rough
//     lockstep -> L1-resident reuse; HBM stream hides under MFMA. No pre-loop
//     barrier, no long-lived staging regs (round-2/6 spill mode eliminated).
//     LDS As holds only h for the GEMM2 tail (v5 epilogue unchanged).
// ---------------------------------------------------------------------------
__global__ __launch_bounds__(640) __attribute__((amdgpu_waves_per_eu(3, 3)))
void k_main(
    const float* __restrict__ X, const u16* __restrict__ W1P,
    const u16* __restrict__ W4P, const float* __restrict__ B1,
    const float* __restrict__ B4, float* __restrict__ OUT)
{
    __shared__ __align__(16) u16 As[64 * STRIDE];        // 103424 B: h tile
    __shared__ __align__(16) float PL2[10 * 4 * 64 * 4]; // 40960 B: GEMM2 partials

    const int t = threadIdx.x;
    const int row0 = blockIdx.x * 64;
    const int l = t & 63, w = t >> 6;
    const int lc = l & 15, lk = l >> 4;

    f32x4 acc[4][5];
    #pragma unroll
    for (int m = 0; m < 4; ++m)
        #pragma unroll
        for (int n = 0; n < 5; ++n) acc[m][n] = (f32x4)(0.0f);

    const short8v* BP = (const short8v*)W1P;
    // per-m A base: row (row0 + m*16 + lc), k-offset lk*8
    const float* xb0 = X + (size_t)(row0 + lc) * NPIX + lk * 8;
    const float* xb1 = xb0 + 16 * NPIX;
    const float* xb2 = xb0 + 32 * NPIX;
    const float* xb3 = xb0 + 48 * NPIX;

    // ---- GEMM1: 25 kt steps, zero barriers, A direct-from-global ----
    #pragma unroll
    for (int kt = 0; kt < 25; ++kt) {
        short8v b[5];
        #pragma unroll
        for (int n = 0; n < 5; ++n)
            b[n] = BP[((w * 5 + n) * 25 + kt) * 64 + l];

        short8v a[4];
        if (kt < 24) {
            const float* p0 = xb0 + kt * 32;
            const float* p1 = xb1 + kt * 32;
            const float* p2 = xb2 + kt * 32;
            const float* p3 = xb3 + kt * 32;
            a[0] = cvt8(*(const float4*)(p0), *(const float4*)(p0 + 4));
            a[1] = cvt8(*(const float4*)(p1), *(const float4*)(p1 + 4));
            a[2] = cvt8(*(const float4*)(p2), *(const float4*)(p2 + 4));
            a[3] = cvt8(*(const float4*)(p3), *(const float4*)(p3 + 4));
        } else {
            // kt=24: k = 768 + lk*8; only lk 0,1 are in-bounds (<784)
            if (lk < 2) {
                const float* p0 = xb0 + 24 * 32;
                const float* p1 = xb1 + 24 * 32;
                const float* p2 = xb2 + 24 * 32;
                const float* p3 = xb3 + 24 * 32;
                a[0] = cvt8(*(const float4*)(p0), *(const float4*)(p0 + 4));
                a[1] = cvt8(*(const float4*)(p1), *(const float4*)(p1 + 4));
                a[2] = cvt8(*(const float4*)(p2), *(const float4*)(p2 + 4));
                a[3] = cvt8(*(const float4*)(p3), *(const float4*)(p3 + 4));
            } else {
                #pragma unroll
                for (int m = 0; m < 4; ++m) a[m] = (short8v)(0);
            }
        }

        __builtin_amdgcn_s_setprio(1);
        #pragma unroll
        for (int m = 0; m < 4; ++m)
            #pragma unroll
            for (int n = 0; n < 5; ++n)
                acc[m][n] = __builtin_amdgcn_mfma_f32_16x16x32_bf16(a[m], b[n], acc[m][n], 0, 0, 0);
        __builtin_amdgcn_s_setprio(0);
    }

    // ---- bias + relu, h (bf16) into As ----
    #pragma unroll
    for (int n = 0; n < 5; ++n) {
        float bn = B1[w * 80 + n * 16 + lc];
        #pragma unroll
        for (int m = 0; m < 4; ++m) {
            #pragma unroll
            for (int j = 0; j < 4; ++j) {
                float hv = fmaxf(acc[m][n][j] + bn, 0.0f);
                As[(m * 16 + lk * 4 + j) * STRIDE + (w * 80 + n * 16 + lc)] = f2bf(hv);
            }
        }
    }
    __syncthreads();   // h complete

    // ---- GEMM2: logits partials via MFMA; wave w covers its kt slice ----
    {
        const int ks  = (w < 5) ? 3 * w : 15 + 2 * (w - 5);
        const int cnt = (w < 5) ? 3 : 2;
        const short8v* WP = (const short8v*)W4P;
        f32x4 pc[4];
        #pragma unroll
        for (int m = 0; m < 4; ++m) pc[m] = (f32x4)(0.0f);
        #pragma unroll
        for (int i = 0; i < 3; ++i) {
            if (i < cnt) {
                int kt = ks + i;
                short8v b = WP[kt * 64 + l];
                #pragma unroll
                for (int m = 0; m < 4; ++m) {
                    short8v a = *(const short8v*)(As + (m * 16 + lc) * STRIDE + kt * 32 + lk * 8);
                    pc[m] = __builtin_amdgcn_mfma_f32_16x16x32_bf16(a, b, pc[m], 0, 0, 0);
                }
            }
        }
        f32x4* PLv = (f32x4*)PL2;
        #pragma unroll
        for (int m = 0; m < 4; ++m)
            PLv[(w * 4 + m) * 64 + l] = pc[m];
    }
    __syncthreads();

    // ---- combine partials + bias + log_softmax, one row per thread ----
    if (t < 64) {
        const int r = t;
        const int m = r >> 4, sub = ((r & 15) >> 2) * 16, j = r & 3;
        float lg[10];
        #pragma unroll
        for (int o = 0; o < 10; ++o) {
            float s = B4[o];
            #pragma unroll
            for (int w2 = 0; w2 < 10; ++w2)
                s += PL2[(((w2 * 4 + m) * 64) + sub + o) * 4 + j];
            lg[o] = s;
        }
        float mx = lg[0];
        #pragma unroll
        for (int o = 1; o < 10; ++o) mx = fmaxf(mx, lg[o]);
        float se = 0.f;
        #pragma unroll
        for (int o = 0; o < 10; ++o) se += expf(lg[o] - mx);
        float lse = logf(se);
        float* op = OUT + (size_t)(row0 + r) * 10;
        #pragma unroll
        for (int o = 0; o < 10; ++o) op[o] = lg[o] - mx - lse;
    }
}

// ---------------------------------------------------------------------------
extern "C" void kernel_launch(void* const* d_in, const int* in_sizes, int n_in,
                              void* d_out, int out_size, void* d_ws, size_t ws_size,
                              hipStream_t stream)
{
    const float* X   = (const float*)d_in[0];
    const float* MRE = (const float*)d_in[1];
    const float* MIM = (const float*)d_in[2];
    const float* W1  = (const float*)d_in[3];
    const float* B1  = (const float*)d_in[4];
    const float* W4  = (const float*)d_in[5];
    const float* B4  = (const float*)d_in[6];
    float* OUT = (float*)d_out;

    float* kre  = (float*)d_ws;                       // 784 f32
    float* flag = kre + 784;                          // 1 f32
    u16*   w1p  = (u16*)((char*)d_ws + 4096);         // 1.28 MB
    u16*   w4p  = (u16*)((char*)d_ws + 4096 + 1310720); // 25.6 KB

    k_kre<<<1, 832, 0, stream>>>(MRE, MIM, kre, flag);
    k_w1pack<<<800, 128, 0, stream>>>(W1, kre, flag, w1p);
    k_w4pack<<<7, 256, 0, stream>>>(W4, w4p);
    k_main<<<512, 640, 0, stream>>>(X, w1p, w4p, B1, B4, OUT);
}

// Round 9
// 72.265 us; speedup vs baseline: 1.7321x; 1.7321x over previous
//
#include <hip/hip_runtime.h>
#include <hip/hip_bf16.h>
#include <cmath>

typedef unsigned short u16;
typedef __attribute__((ext_vector_type(8))) short short8v;
typedef __attribute__((ext_vector_type(4))) unsigned short ushort4v;
typedef __attribute__((ext_vector_type(8))) unsigned short ushort8v;
typedef __attribute__((ext_vector_type(4))) float f32x4;

#define NPIX 784      // 28*28
#define KP   800      // padded K (25 k-frags of 32)
#define NH   800      // HID
#define STRIDE 808    // h-tile LDS row stride, bf16 elems (1616 B rows)
#define CHB  40960    // X chunk bytes: 64 rows x 160 f32 (640 B), linear
#define ROWB 640      // X chunk row bytes

__device__ __forceinline__ u16 f2bf(float f) {
    union { float f; unsigned int u; } v; v.f = f;
    unsigned int u = v.u;
    unsigned int r = (u + 0x7FFFu + ((u >> 16) & 1u)) >> 16;   // RNE
    return (u16)r;
}

__device__ __forceinline__ short8v cvt8(f32x4 v0, f32x4 v1) {
    union { __hip_bfloat162 h; ushort2 u; } a, b, c, d;
    a.h = __float22bfloat162_rn(make_float2(v0[0], v0[1]));
    b.h = __float22bfloat162_rn(make_float2(v0[2], v0[3]));
    c.h = __float22bfloat162_rn(make_float2(v1[0], v1[1]));
    d.h = __float22bfloat162_rn(make_float2(v1[2], v1[3]));
    short8v r;
    r[0] = (short)a.u.x; r[1] = (short)a.u.y; r[2] = (short)b.u.x; r[3] = (short)b.u.y;
    r[4] = (short)c.u.x; r[5] = (short)c.u.y; r[6] = (short)d.u.x; r[7] = (short)d.u.y;
    return r;
}

// async global->LDS, 16 B/lane, no VGPR data round-trip
__device__ __forceinline__ void gload16(const float* g, void* l) {
    __builtin_amdgcn_global_load_lds(
        (const __attribute__((address_space(1))) unsigned int*)g,
        (__attribute__((address_space(3))) unsigned int*)l,
        16, 0, 0);
}

// ---------------------------------------------------------------------------
// Kernel 1: kre = Re(ifft2(ifftshift(tmask))); flag=1 if kre == delta.
// ---------------------------------------------------------------------------
__global__ void k_kre(const float* __restrict__ MRE, const float* __restrict__ MIM,
                      float* __restrict__ KRE, float* __restrict__ FLAG)
{
    __shared__ float msre[784], msim[784], tre[784], tim[784];
    __shared__ float c28[28], s28[28];
    __shared__ int smax;

    const int t = threadIdx.x;   // blockDim = 832
    if (t < 28) {
        float th = (float)t * (6.283185307179586f / 28.0f);
        s28[t] = sinf(th);
        c28[t] = cosf(th);
    }
    if (t == 0) smax = 0;
    if (t < 784) {
        int r = t / 28, c = t - r * 28;
        int idx = ((r + 14) % 28) * 28 + ((c + 14) % 28);   // ifftshift
        msre[t] = MRE[idx];
        msim[t] = MIM[idx];
    }
    __syncthreads();
    if (t < 784) {
        int u = t / 28, cc = t - u * 28;
        float re = 0.f, im = 0.f;
        int ph = 0;
        for (int v = 0; v < 28; ++v) {
            float cr = c28[ph], ci = s28[ph];
            float ar = msre[u * 28 + v], ai = msim[u * 28 + v];
            re += ar * cr - ai * ci;
            im += ar * ci + ai * cr;
            ph += cc; if (ph >= 28) ph -= 28;
        }
        tre[t] = re; tim[t] = im;
    }
    __syncthreads();
    float dev = 0.f;
    if (t < 784) {
        int pr = t / 28, pc = t - pr * 28;
        float s = 0.f;
        int ph = 0;
        for (int u = 0; u < 28; ++u) {
            s += tre[u * 28 + pc] * c28[ph] - tim[u * 28 + pc] * s28[ph];
            ph += pr; if (ph >= 28) ph -= 28;
        }
        s *= (1.0f / 784.0f);
        KRE[t] = s;
        dev = fabsf(s - (t == 0 ? 1.0f : 0.0f));
    }
    #pragma unroll
    for (int m = 32; m >= 1; m >>= 1) dev = fmaxf(dev, __shfl_xor(dev, m, 64));
    if ((t & 63) == 0) atomicMax(&smax, __float_as_int(dev));
    __syncthreads();
    if (t == 0) FLAG[0] = (__int_as_float(smax) < 1e-4f) ? 1.0f : 0.0f;
}

// ---------------------------------------------------------------------------
// Kernel 2: w1_eff packed into MFMA B-fragment order, bf16 (k>=784 -> 0).
// ---------------------------------------------------------------------------
__global__ void k_w1pack(const float* __restrict__ W1, const float* __restrict__ KRE,
                         const float* __restrict__ FLAG, u16* __restrict__ W1P)
{
    const int c = blockIdx.x;    // 0..799
    const int t = threadIdx.x;   // 128
    const bool delta = (FLAG[0] > 0.5f);
    __shared__ float w1d[56 * 56];
    __shared__ float kr[784];

    if (delta) {
        if (t < 100) {
            int k0 = t * 8;
            ushort8v h;
            if (k0 + 7 < NPIX) {
                const float4* wp = (const float4*)(W1 + (size_t)c * NPIX + k0);
                float4 a = wp[0], b = wp[1];
                h[0] = f2bf(a.x); h[1] = f2bf(a.y); h[2] = f2bf(a.z); h[3] = f2bf(a.w);
                h[4] = f2bf(b.x); h[5] = f2bf(b.y); h[6] = f2bf(b.z); h[7] = f2bf(b.w);
            } else {
                #pragma unroll
                for (int e = 0; e < 8; ++e) {
                    int k = k0 + e;
                    h[e] = (k < NPIX) ? f2bf(W1[(size_t)c * NPIX + k]) : (u16)0;
                }
            }
            int kf = k0 >> 5, r = k0 & 31;
            int l  = ((r >> 3) << 4) | (c & 15);
            int nf = c >> 4;
            ((ushort8v*)W1P)[(nf * 25 + kf) * 64 + l] = h;
        }
        return;
    }
    for (int i = t; i < 784; i += 128) kr[i] = KRE[i];
    for (int i = t; i < 3136; i += 128) {
        int r = i / 56, cc = i - r * 56;
        w1d[i] = W1[(size_t)c * NPIX + (r % 28) * 28 + (cc % 28)];
    }
    __syncthreads();
    for (int k = t; k < KP; k += 128) {
        float v = 0.f;
        if (k < NPIX) {
            int krr = k / 28, kcc = k - krr * 28;
            for (int dr = 0; dr < 28; ++dr) {
                const float* wrow = &w1d[(krr + dr) * 56 + kcc];
                const float* krow = &kr[dr * 28];
                #pragma unroll 4
                for (int dc = 0; dc < 28; ++dc) v += wrow[dc] * krow[dc];
            }
        }
        int kf = k >> 5, r = k & 31;
        int l  = ((r >> 3) << 4) | (c & 15);
        int nf = c >> 4;
        W1P[(size_t)(((nf * 25 + kf) * 64 + l) << 3) | (r & 7)] = f2bf(v);
    }
}

// ---------------------------------------------------------------------------
// Kernel 2b: pack W4 into B-fragment order, 16-col tile, cols 10..15 zero.
// ---------------------------------------------------------------------------
__global__ void k_w4pack(const float* __restrict__ W4, u16* __restrict__ W4P)
{
    int i = blockIdx.x * 256 + threadIdx.x;   // (kt*64 + l), 1600 total
    if (i >= 1600) return;
    int l = i & 63, kt = i >> 6;
    int lc = l & 15, lk = l >> 4;
    ushort8v h;
    #pragma unroll
    for (int e = 0; e < 8; ++e) {
        int k = kt * 32 + lk * 8 + e;
        h[e] = (lc < 10) ? f2bf(W4[lc * NH + k]) : (u16)0;
    }
    ((ushort8v*)W4P)[i] = h;
}

// ---------------------------------------------------------------------------
// Kernel 3: fused GEMM1 + relu + (MFMA) GEMM2 + log_softmax.
// v9 = v8 with the de-swizzle fix: read already de-swizzles via address XOR,
//     so A halves are ALWAYS (v0, v1) — the conditional swap was the bug.
//     Plus sched_barrier(0) hoist-guards after the post-stage barriers.
// ---------------------------------------------------------------------------
__global__ __launch_bounds__(640) __attribute__((amdgpu_waves_per_eu(3, 3)))
void k_main(
    const float* __restrict__ X, const u16* __restrict__ W1P,
    const u16* __restrict__ W4P, const float* __restrict__ B1,
    const float* __restrict__ B4, float* __restrict__ OUT)
{
    __shared__ __align__(16) char SMEM[144384];
    char*  xb0 = SMEM;                 // X chunk buf 0 (40960 B), GEMM1 phase
    char*  xb1 = SMEM + CHB;           // X chunk buf 1 (40960 B)
    u16*   As  = (u16*)SMEM;           // overlay: h tile (103424 B), post-GEMM1
    float* PL2 = (float*)(SMEM + 103424); // overlay: GEMM2 partials (40960 B)

    const int t = threadIdx.x;
    const int row0 = blockIdx.x * 64;
    const int l = t & 63, w = t >> 6;
    const int lc = l & 15, lk = l >> 4;

    // ---- staging geometry: 2560 slots of 16B, exactly 4 per thread ----
    const int r0s  = t / 40;                 // base row (0..15); +16 per issue
    const int cs16 = (t - r0s * 40) * 16;    // LDS byte col (linear)
    const int swzS = (r0s & 7) << 4;         // row&7 invariant under +16
    const int colb = cs16 ^ swzS;            // global byte col in 640B row
    const bool ok4 = colb < 576;             // chunk4 data = 144 f32 = 576B
    const float* gp[4];
    #pragma unroll
    for (int i = 0; i < 4; ++i)
        gp[i] = X + (size_t)(row0 + r0s + 16 * i) * NPIX + (colb >> 2);
    const int lb = 16 * t;                   // LDS byte offset of slot i=0

    // ---- A-read geometry (swizzled) ----
    const int swzA = (lc & 7) << 4;
    const int q0 = (lk * 32) ^ swzA;
    const int q1 = q0 ^ 16;
    const int arow = lc * ROWB;

    f32x4 acc[4][5];
    #pragma unroll
    for (int m = 0; m < 4; ++m)
        #pragma unroll
        for (int n = 0; n < 5; ++n) acc[m][n] = (f32x4)(0.0f);

    const short8v* BP = (const short8v*)W1P;
    short8v bb[2][5];
    #pragma unroll
    for (int n = 0; n < 5; ++n)
        bb[0][n] = BP[((w * 5 + n) * 25 + 0) * 64 + l];
    __builtin_amdgcn_sched_barrier(0);       // keep bb loads older than stages

    // ---- prologue: stage chunk 0 -> xb0, chunk 1 -> xb1 ----
    #pragma unroll
    for (int i = 0; i < 4; ++i) gload16(gp[i], xb0 + lb + i * 10240);
    #pragma unroll
    for (int i = 0; i < 4; ++i) gload16(gp[i] + 160, xb1 + lb + i * 10240);
    asm volatile("s_waitcnt vmcnt(4)" ::: "memory");   // chunk0 (+bb) landed
    __builtin_amdgcn_s_barrier();
    __builtin_amdgcn_sched_barrier(0);

    // ---- GEMM1: 5 chunks x 5 kt, double-buffered, counted vmcnt ----
    #pragma unroll
    for (int c = 0; c < 5; ++c) {
        const char* bufc = (c & 1) ? xb1 : xb0;
        #pragma unroll
        for (int kf = 0; kf < 5; ++kf) {
            const int kt = c * 5 + kf;
            if (kt < 24) {
                #pragma unroll
                for (int n = 0; n < 5; ++n)
                    bb[(kt + 1) & 1][n] = BP[((w * 5 + n) * 25 + (kt + 1)) * 64 + l];
            }
            const char* ab = bufc + arow + kf * 128;
            __builtin_amdgcn_s_setprio(1);
            #pragma unroll
            for (int m = 0; m < 4; ++m) {
                f32x4 v0 = *(const f32x4*)(ab + m * 10240 + q0);
                f32x4 v1 = *(const f32x4*)(ab + m * 10240 + q1);
                short8v a = cvt8(v0, v1);   // address XOR already de-swizzled
                #pragma unroll
                for (int n = 0; n < 5; ++n)
                    acc[m][n] = __builtin_amdgcn_mfma_f32_16x16x32_bf16(a, bb[kt & 1][n], acc[m][n], 0, 0, 0);
            }
            __builtin_amdgcn_s_setprio(0);
        }
        if (c < 4) {
            __builtin_amdgcn_sched_barrier(0);     // pin compute above stage
            __builtin_amdgcn_s_barrier();          // all reads of bufc done
            if (c < 3) {
                char* dst = (c & 1) ? xb1 : xb0;
                const int ch = c + 2;
                #pragma unroll
                for (int i = 0; i < 4; ++i) {
                    const float* g = (ch == 4 && !ok4) ? X : gp[i] + ch * 160;
                    gload16(g, dst + lb + i * 10240);
                }
                asm volatile("s_waitcnt vmcnt(4)" ::: "memory");  // S(c+1) landed
            } else {
                asm volatile("s_waitcnt vmcnt(5)" ::: "memory");  // S4 landed (5 bb fly)
            }
            __builtin_amdgcn_s_barrier();          // everyone's S(c+1) landed
            __builtin_amdgcn_sched_barrier(0);     // no ds_read hoists above
        }
    }
    __syncthreads();   // all chunk reads done; safe to overwrite with h

    // ---- bias + relu, h (bf16) into As ----
    #pragma unroll
    for (int n = 0; n < 5; ++n) {
        float bn = B1[w * 80 + n * 16 + lc];
        #pragma unroll
        for (int m = 0; m < 4; ++m) {
            #pragma unroll
            for (int j = 0; j < 4; ++j) {
                float hv = fmaxf(acc[m][n][j] + bn, 0.0f);
                As[(m * 16 + lk * 4 + j) * STRIDE + (w * 80 + n * 16 + lc)] = f2bf(hv);
            }
        }
    }
    __syncthreads();   // h complete

    // ---- GEMM2: logits partials via MFMA; wave w covers its kt slice ----
    {
        const int ks  = (w < 5) ? 3 * w : 15 + 2 * (w - 5);
        const int cnt = (w < 5) ? 3 : 2;
        const short8v* WP = (const short8v*)W4P;
        f32x4 pc[4];
        #pragma unroll
        for (int m = 0; m < 4; ++m) pc[m] = (f32x4)(0.0f);
        #pragma unroll
        for (int i = 0; i < 3; ++i) {
            if (i < cnt) {
                int kt = ks + i;
                short8v b = WP[kt * 64 + l];
                #pragma unroll
                for (int m = 0; m < 4; ++m) {
                    short8v a = *(const short8v*)(As + (m * 16 + lc) * STRIDE + kt * 32 + lk * 8);
                    pc[m] = __builtin_amdgcn_mfma_f32_16x16x32_bf16(a, b, pc[m], 0, 0, 0);
                }
            }
        }
        f32x4* PLv = (f32x4*)PL2;
        #pragma unroll
        for (int m = 0; m < 4; ++m)
            PLv[(w * 4 + m) * 64 + l] = pc[m];
    }
    __syncthreads();

    // ---- combine partials + bias + log_softmax, one row per thread ----
    if (t < 64) {
        const int r = t;
        const int m = r >> 4, sub = ((r & 15) >> 2) * 16, j = r & 3;
        float lg[10];
        #pragma unroll
        for (int o = 0; o < 10; ++o) {
            float s = B4[o];
            #pragma unroll
            for (int w2 = 0; w2 < 10; ++w2)
                s += PL2[(((w2 * 4 + m) * 64) + sub + o) * 4 + j];
            lg[o] = s;
        }
        float mx = lg[0];
        #pragma unroll
        for (int o = 1; o < 10; ++o) mx = fmaxf(mx, lg[o]);
        float se = 0.f;
        #pragma unroll
        for (int o = 0; o < 10; ++o) se += expf(lg[o] - mx);
        float lse = logf(se);
        float* op = OUT + (size_t)(row0 + r) * 10;
        #pragma unroll
        for (int o = 0; o < 10; ++o) op[o] = lg[o] - mx - lse;
    }
}

// ---------------------------------------------------------------------------
extern "C" void kernel_launch(void* const* d_in, const int* in_sizes, int n_in,
                              void* d_out, int out_size, void* d_ws, size_t ws_size,
                              hipStream_t stream)
{
    const float* X   = (const float*)d_in[0];
    const float* MRE = (const float*)d_in[1];
    const float* MIM = (const float*)d_in[2];
    const float* W1  = (const float*)d_in[3];
    const float* B1  = (const float*)d_in[4];
    const float* W4  = (const float*)d_in[5];
    const float* B4  = (const float*)d_in[6];
    float* OUT = (float*)d_out;

    float* kre  = (float*)d_ws;                         // 784 f32
    float* flag = kre + 784;                            // 1 f32
    u16*   w1p  = (u16*)((char*)d_ws + 4096);           // 1.28 MB
    u16*   w4p  = (u16*)((char*)d_ws + 4096 + 1310720); // 25.6 KB

    k_kre<<<1, 832, 0, stream>>>(MRE, MIM, kre, flag);
    k_w1pack<<<800, 128, 0, stream>>>(W1, kre, flag, w1p);
    k_w4pack<<<7, 256, 0, stream>>>(W4, w4p);
    k_main<<<512, 640, 0, stream>>>(X, w1p, w4p, B1, B4, OUT);
}